// Round 1
// baseline (3051.687 us; speedup 1.0000x reference)
//
#include <hip/hip_runtime.h>

// Problem constants (match reference file)
#define NT 262144          // N = B*NBUS total nodes
#define NB 512             // NBUS
#define NE 2097152         // E edges

// ---------------------------------------------------------------------------
// den[i] = ybus[b, j, j] * 100  (diagonal only);  p[i] = x[i,0] - x[i,1]
__global__ void setup_kernel(const float* __restrict__ x,
                             const float* __restrict__ ybus,
                             float* __restrict__ den,
                             float* __restrict__ p) {
    int i = blockIdx.x * blockDim.x + threadIdx.x;
    if (i >= NT) return;
    int b = i >> 9;            // graph
    int j = i & (NB - 1);      // bus
    den[i] = ybus[(size_t)b * (NB * NB) + (size_t)j * (NB + 1)] * 100.0f;
    float2 xv = ((const float2*)x)[i];
    p[i] = xv.x - xv.y;
}

// ---------------------------------------------------------------------------
// aggr[dst[e]] += theta[src[e]] * (attr[e]*100)
__global__ void propagate_kernel(const float* __restrict__ theta,
                                 const int* __restrict__ src,
                                 const int* __restrict__ dst,
                                 const float* __restrict__ attr,
                                 float* __restrict__ aggr) {
    int e = blockIdx.x * blockDim.x + threadIdx.x;
    if (e >= NE) return;
    float w = attr[e] * 100.0f;
    atomicAdd(&aggr[dst[e]], theta[src[e]] * w);
}

// ---------------------------------------------------------------------------
// t_i = (den!=0) ? (p - aggr)/den : 0 ; theta = (den!=0) ? t_i - t_ref : 0
// t_ref recomputed by every thread from its graph's ref node (bus 0): the
// reads of aggr/p/den at the ref node are a per-graph broadcast (cache hit).
__global__ void layer_finish_kernel(const float* __restrict__ aggr,
                                    const float* __restrict__ p,
                                    const float* __restrict__ den,
                                    float* __restrict__ theta) {
    int i = blockIdx.x * blockDim.x + threadIdx.x;
    if (i >= NT) return;
    float d = den[i];
    float t = (d != 0.0f) ? (p[i] - aggr[i]) / d : 0.0f;
    int base = i & ~(NB - 1);          // ref node of this graph (REF_NODE=0)
    float dr = den[base];
    float tr = (dr != 0.0f) ? (p[base] - aggr[base]) / dr : 0.0f;
    theta[i] = (d != 0.0f) ? (t - tr) : 0.0f;
}

// ---------------------------------------------------------------------------
// err[k] += sum_i |p_i - aggr_i|   (block tree reduce, one float atomic/block;
// all-positive sum -> fp32 accumulation is well inside the 2% threshold)
__global__ void error_kernel(const float* __restrict__ aggr,
                             const float* __restrict__ p,
                             float* __restrict__ err, int k) {
    int i = blockIdx.x * blockDim.x + threadIdx.x;
    float v = (i < NT) ? fabsf(p[i] - aggr[i]) : 0.0f;
    #pragma unroll
    for (int off = 32; off > 0; off >>= 1)
        v += __shfl_down(v, off, 64);
    __shared__ float wsum[4];
    int lane = threadIdx.x & 63, wv = threadIdx.x >> 6;
    if (lane == 0) wsum[wv] = v;
    __syncthreads();
    if (threadIdx.x == 0) {
        atomicAdd(&err[k], wsum[0] + wsum[1] + wsum[2] + wsum[3]);
    }
}

// ---------------------------------------------------------------------------
__global__ void finalize_kernel(const float* __restrict__ theta,
                                const float* __restrict__ err,
                                float* __restrict__ out) {
    int i = blockIdx.x * blockDim.x + threadIdx.x;
    if (i < NT) out[i] = theta[i];
    else if (i < NT + 11) out[i] = err[i - NT];
}

// ---------------------------------------------------------------------------
extern "C" void kernel_launch(void* const* d_in, const int* in_sizes, int n_in,
                              void* d_out, int out_size, void* d_ws, size_t ws_size,
                              hipStream_t stream) {
    const float* x     = (const float*)d_in[0];
    // d_in[1] = y, only used for shape in the reference -> unused
    const float* ybus  = (const float*)d_in[2];
    const int*   ei_nd = (const int*)d_in[3];   // edge_index_no_diag [2,E]
    const float* ea_nd = (const float*)d_in[4]; // edge_attr_no_diag  [E]
    const int*   ei    = (const int*)d_in[5];   // edge_index         [2,E]
    const float* ea    = (const float*)d_in[6]; // edge_attr          [E]
    float* out = (float*)d_out;

    float* ws    = (float*)d_ws;
    float* den   = ws;
    float* p     = ws + NT;
    float* theta = ws + 2 * (size_t)NT;
    float* aggr  = ws + 3 * (size_t)NT;
    float* err   = ws + 4 * (size_t)NT;   // 11 floats

    const int TPB = 256;
    const int gN  = (NT + TPB - 1) / TPB;     // 1024
    const int gE  = (NE + TPB - 1) / TPB;     // 8192

    hipMemsetAsync(err, 0, 11 * sizeof(float), stream);
    setup_kernel<<<gN, TPB, 0, stream>>>(x, ybus, den, p);

    for (int k = 0; k < 11; ++k) {
        hipMemsetAsync(aggr, 0, NT * sizeof(float), stream);
        if (k > 0) {
            // theta holds previous layer output
            propagate_kernel<<<gE, TPB, 0, stream>>>(theta, ei_nd, ei_nd + NE,
                                                     ea_nd, aggr);
        }
        // k == 0: theta ≡ 0 -> aggr stays 0, matching the reference
        layer_finish_kernel<<<gN, TPB, 0, stream>>>(aggr, p, den, theta);

        hipMemsetAsync(aggr, 0, NT * sizeof(float), stream);
        propagate_kernel<<<gE, TPB, 0, stream>>>(theta, ei, ei + NE, ea, aggr);
        error_kernel<<<gN, TPB, 0, stream>>>(aggr, p, err, k);
    }

    finalize_kernel<<<gN + 1, TPB, 0, stream>>>(theta, err, out);
}